// Round 2
// 1625.874 us; speedup vs baseline: 1.0438x; 1.0438x over previous
//
#include <hip/hip_runtime.h>
#include <hip/hip_bf16.h>

#define TOKENS 8192
#define HID 4096
#define NEXP 8
#define INTER 2048
#define VOCABM1 31999
#define MAXROWS 9216          // 8192 + 8*128 padding
#define MAXTILES 72

typedef float f32x4 __attribute__((ext_vector_type(4)));
typedef __bf16 bf16x8 __attribute__((ext_vector_type(8)));
typedef short sh4 __attribute__((ext_vector_type(4)));

// ---- workspace layout (byte offsets) ----
#define WS_NTILES  0
#define WS_TEXP    64
#define WS_TROW    512
#define WS_TNV     1024
#define WS_PERM    4096
#define WS_ROWTOK  40960
#define WS_XS      131072
#define WS_INTER   (WS_XS + (size_t)MAXROWS * HID * 2)                 // sorted x, bf16
#define WS_GUPT    (WS_INTER + (size_t)MAXROWS * INTER * 2)            // swiglu out, bf16
// gate_up^T bf16 [e][n][k] lives at WS_GUPT (268 MB). down^T bf16 [e][n][k]
// (134 MB) REUSES the same region: on a single stream convT(dwn) launches after
// gemm1_bf has consumed gate_up^T, so the overwrite is safe and saves 134 MB.
#define WS_DWNT    WS_GUPT
#define WS_NEED_BIG (WS_GUPT + (size_t)NEXP * (2 * INTER) * HID * 2)
#define WS_NEED_SMALL WS_GUPT

__device__ __forceinline__ int iclamp(int v, int lo, int hi) {
    return v < lo ? lo : (v > hi ? hi : v);
}
__device__ __forceinline__ unsigned short f2b(float f) {
    __hip_bfloat16 h = __float2bfloat16(f);
    unsigned short u; __builtin_memcpy(&u, &h, 2); return u;
}
__device__ __forceinline__ unsigned pk2(float a, float b) {
    return (unsigned)f2b(a) | ((unsigned)f2b(b) << 16);
}
__device__ __forceinline__ void gld16(const void* g, void* l) {
    __builtin_amdgcn_global_load_lds((const __attribute__((address_space(1))) void*)g,
                                     (__attribute__((address_space(3))) void*)l,
                                     16, 0, 0);
}
__device__ __forceinline__ bf16x8 ldfrag(const unsigned short* p) {
    sh4 lo = *(const sh4*)p;
    sh4 hi = *(const sh4*)(p + 4);
    struct { sh4 a, b; } s{lo, hi};
    return __builtin_bit_cast(bf16x8, s);
}

// ---------------- routing ----------------
__global__ void route_kernel(const int* __restrict__ ids, char* __restrict__ ws) {
    __shared__ int cnt[NEXP], base[NEXP], cur[NEXP];
    int tid = threadIdx.x;
    if (tid < NEXP) { cnt[tid] = 0; cur[tid] = 0; }
    __syncthreads();
    for (int i = tid; i < TOKENS; i += blockDim.x) {
        int v = iclamp(ids[i], 0, VOCABM1);
        atomicAdd(&cnt[v & 7], 1);
    }
    __syncthreads();
    if (tid == 0) {
        int* texp = (int*)(ws + WS_TEXP);
        int* trow = (int*)(ws + WS_TROW);
        int* tnv  = (int*)(ws + WS_TNV);
        int pb = 0, ntl = 0;
        for (int e = 0; e < NEXP; e++) {
            base[e] = pb;
            int ne = cnt[e];
            int t = (ne + 127) >> 7;
            for (int j = 0; j < t; j++) {
                texp[ntl] = e;
                trow[ntl] = pb + j * 128;
                int rem = ne - j * 128;
                tnv[ntl] = rem < 128 ? rem : 128;
                ntl++;
            }
            pb += t * 128;
        }
        *(int*)(ws + WS_NTILES) = ntl;
    }
    __syncthreads();
    int* perm = (int*)(ws + WS_PERM);
    int* rt   = (int*)(ws + WS_ROWTOK);
    for (int i = tid; i < TOKENS; i += blockDim.x) {
        int v = iclamp(ids[i], 0, VOCABM1);
        int e = v & 7;
        int p = atomicAdd(&cur[e], 1);
        int slot = base[e] + p;
        perm[i] = slot;
        rt[slot] = i;
    }
}

// ---------------- gather + fp32->bf16 cast of x into sorted order ----------------
__global__ void gather_cast(const float* __restrict__ x, char* __restrict__ ws) {
    const int* perm = (const int*)(ws + WS_PERM);
    unsigned short* xs = (unsigned short*)(ws + WS_XS);
    int tok = blockIdx.x;
    int slot = perm[tok];
    const float4* src = (const float4*)(x + (size_t)tok * HID);
    uint2* dst = (uint2*)(xs + (size_t)slot * HID);
    for (int j = threadIdx.x; j < HID / 4; j += blockDim.x) {
        float4 f = src[j];
        dst[j] = make_uint2(pk2(f.x, f.y), pk2(f.z, f.w));
    }
}

// ---------------- convert + transpose weights: fp32 [e][R][C] -> bf16 [e][C][R] ----------------
// grid (C/64, R/64, NEXP), block 256. fp32 LDS tile [64][65]: conflict-free both
// phases; coalesced global read (256B runs) and write (128B runs per row).
__global__ __launch_bounds__(256)
void convT_kernel(const float* __restrict__ src, unsigned short* __restrict__ dst,
                  int R, int C) {
    __shared__ float tile[64][65];
    int e = blockIdx.z;
    const float* S = src + (size_t)e * R * C;
    unsigned short* D = dst + (size_t)e * C * R;
    int r0 = blockIdx.y * 64, c0 = blockIdx.x * 64;
    int t = threadIdx.x;
    int lr = t >> 4;            // 0..15
    int lc = (t & 15) * 4;      // 0..60
#pragma unroll
    for (int i = 0; i < 4; i++) {
        int rr = lr + i * 16;
        float4 v = *(const float4*)(S + (size_t)(r0 + rr) * C + c0 + lc);
        tile[rr][lc + 0] = v.x; tile[rr][lc + 1] = v.y;
        tile[rr][lc + 2] = v.z; tile[rr][lc + 3] = v.w;
    }
    __syncthreads();
#pragma unroll
    for (int i = 0; i < 2; i++) {
        int g = t + i * 256;
        int n = g >> 3;           // 0..63 output row (col of src)
        int kg = (g & 7) * 8;     // k offset, 8 elems = 16B
        uint4 o;
        o.x = pk2(tile[kg + 0][n], tile[kg + 1][n]);
        o.y = pk2(tile[kg + 2][n], tile[kg + 3][n]);
        o.z = pk2(tile[kg + 4][n], tile[kg + 5][n]);
        o.w = pk2(tile[kg + 6][n], tile[kg + 7][n]);
        *(uint4*)(D + (size_t)(c0 + n) * R + r0 + kg) = o;
    }
}

// ---------------- GEMM1 (bf16 weights): xs @ gate_up^T + SwiGLU -> inter ----------------
// m97 structure: all tiles staged linear [128][32] via global_load_lds width=16.
__global__ __launch_bounds__(256, 2)
void gemm1_bf(char* __restrict__ ws) {
    int nt = *(const int*)(ws + WS_NTILES);
    int by = blockIdx.y;
    if (by >= nt) return;
    int e    = ((const int*)(ws + WS_TEXP))[by];
    int row0 = ((const int*)(ws + WS_TROW))[by];
    int nv   = ((const int*)(ws + WS_TNV))[by];

    const unsigned short* xs   = (const unsigned short*)(ws + WS_XS);
    const unsigned short* gupT = (const unsigned short*)(ws + WS_GUPT);
    unsigned short* ib = (unsigned short*)(ws + WS_INTER);

    __shared__ __align__(16) unsigned short sA [128 * 32];
    __shared__ __align__(16) unsigned short sBg[128 * 32];
    __shared__ __align__(16) unsigned short sBu[128 * 32];

    int tid = threadIdx.x, w = tid >> 6, l = tid & 63;
    int wm = w & 1, wn = w >> 1, m = l & 15, q = l >> 4;

    const unsigned short* Ab = xs + (size_t)row0 * HID;
    const unsigned short* Bg = gupT + ((size_t)e * (2 * INTER) + blockIdx.x * 128) * HID;
    const unsigned short* Bu = Bg + (size_t)INTER * HID;

    size_t a0 = (size_t)(tid >> 2) * HID + (tid & 3) * 8;
    size_t a1 = a0 + (size_t)64 * HID;
    int d0 = w * 512, d1 = 2048 + w * 512;   // wave-uniform LDS dest (elems)

    f32x4 accg[4][4], accu[4][4];
#pragma unroll
    for (int i = 0; i < 4; i++)
#pragma unroll
        for (int j = 0; j < 4; j++) { accg[i][j] = (f32x4)0.0f; accu[i][j] = (f32x4)0.0f; }

    for (int k0 = 0; k0 < HID; k0 += 32) {
        gld16(Ab + a0 + k0, sA + d0);
        gld16(Ab + a1 + k0, sA + d1);
        gld16(Bg + a0 + k0, sBg + d0);
        gld16(Bg + a1 + k0, sBg + d1);
        gld16(Bu + a0 + k0, sBu + d0);
        gld16(Bu + a1 + k0, sBu + d1);
        __syncthreads();

        bf16x8 af[4], bg[4], bu[4];
#pragma unroll
        for (int mi = 0; mi < 4; mi++)
            af[mi] = *(const bf16x8*)(sA + (wm * 64 + mi * 16 + m) * 32 + q * 8);
#pragma unroll
        for (int ni = 0; ni < 4; ni++) {
            int nb = (wn * 64 + ni * 16 + m) * 32 + q * 8;
            bg[ni] = *(const bf16x8*)(sBg + nb);
            bu[ni] = *(const bf16x8*)(sBu + nb);
        }
#pragma unroll
        for (int mi = 0; mi < 4; mi++)
#pragma unroll
            for (int ni = 0; ni < 4; ni++) {
                accg[mi][ni] = __builtin_amdgcn_mfma_f32_16x16x32_bf16(af[mi], bg[ni], accg[mi][ni], 0, 0, 0);
                accu[mi][ni] = __builtin_amdgcn_mfma_f32_16x16x32_bf16(af[mi], bu[ni], accu[mi][ni], 0, 0, 0);
            }
        __syncthreads();
    }

#pragma unroll
    for (int mi = 0; mi < 4; mi++)
#pragma unroll
        for (int r = 0; r < 4; r++) {
            int rl = wm * 64 + mi * 16 + q * 4 + r;
            if (rl < nv) {
                size_t o = (size_t)(row0 + rl) * INTER + blockIdx.x * 128 + wn * 64 + m;
#pragma unroll
                for (int ni = 0; ni < 4; ni++) {
                    float g = accg[mi][ni][r];
                    float u = accu[mi][ni][r];
                    float s = g / (1.0f + __expf(-g));
                    ib[o + ni * 16] = f2b(s * u);
                }
            }
        }
}

// ---------------- GEMM2 (bf16 weights): inter @ down^T -> scatter to out ----------------
__global__ __launch_bounds__(256, 2)
void gemm2_bf(char* __restrict__ ws, float* __restrict__ out) {
    int nt = *(const int*)(ws + WS_NTILES);
    int by = blockIdx.y;
    if (by >= nt) return;
    int e    = ((const int*)(ws + WS_TEXP))[by];
    int row0 = ((const int*)(ws + WS_TROW))[by];
    int nv   = ((const int*)(ws + WS_TNV))[by];
    const int* rowtok = (const int*)(ws + WS_ROWTOK);
    const unsigned short* ib   = (const unsigned short*)(ws + WS_INTER);
    const unsigned short* dwnT = (const unsigned short*)(ws + WS_DWNT);

    __shared__ __align__(16) unsigned short sA[128 * 32];
    __shared__ __align__(16) unsigned short sB[128 * 32];

    int tid = threadIdx.x, w = tid >> 6, l = tid & 63;
    int wm = w & 1, wn = w >> 1, m = l & 15, q = l >> 4;

    const unsigned short* Ab = ib + (size_t)row0 * INTER;
    const unsigned short* Bb = dwnT + ((size_t)e * HID + blockIdx.x * 128) * INTER;

    size_t a0 = (size_t)(tid >> 2) * INTER + (tid & 3) * 8;
    size_t a1 = a0 + (size_t)64 * INTER;
    int d0 = w * 512, d1 = 2048 + w * 512;

    f32x4 acc[4][4];
#pragma unroll
    for (int i = 0; i < 4; i++)
#pragma unroll
        for (int j = 0; j < 4; j++) acc[i][j] = (f32x4)0.0f;

    for (int k0 = 0; k0 < INTER; k0 += 32) {
        gld16(Ab + a0 + k0, sA + d0);
        gld16(Ab + a1 + k0, sA + d1);
        gld16(Bb + a0 + k0, sB + d0);
        gld16(Bb + a1 + k0, sB + d1);
        __syncthreads();

        bf16x8 af[4], bfr[4];
#pragma unroll
        for (int mi = 0; mi < 4; mi++)
            af[mi] = *(const bf16x8*)(sA + (wm * 64 + mi * 16 + m) * 32 + q * 8);
#pragma unroll
        for (int ni = 0; ni < 4; ni++)
            bfr[ni] = *(const bf16x8*)(sB + (wn * 64 + ni * 16 + m) * 32 + q * 8);
#pragma unroll
        for (int mi = 0; mi < 4; mi++)
#pragma unroll
            for (int ni = 0; ni < 4; ni++)
                acc[mi][ni] = __builtin_amdgcn_mfma_f32_16x16x32_bf16(af[mi], bfr[ni], acc[mi][ni], 0, 0, 0);
        __syncthreads();
    }

#pragma unroll
    for (int mi = 0; mi < 4; mi++)
#pragma unroll
        for (int r = 0; r < 4; r++) {
            int rl = wm * 64 + mi * 16 + q * 4 + r;
            if (rl < nv) {
                int tok = rowtok[row0 + rl];
                size_t o = (size_t)tok * HID + blockIdx.x * 128 + wn * 64 + m;
#pragma unroll
                for (int ni = 0; ni < 4; ni++) out[o + ni * 16] = acc[mi][ni][r];
            }
        }
}

// ================= fallback path (verified previous kernels, fp32 weights) =================
__global__ __launch_bounds__(256, 2)
void gemm1_f32(char* __restrict__ ws, const float* __restrict__ gup) {
    int nt = *(const int*)(ws + WS_NTILES);
    int by = blockIdx.y;
    if (by >= nt) return;
    int e    = ((const int*)(ws + WS_TEXP))[by];
    int row0 = ((const int*)(ws + WS_TROW))[by];
    int nv   = ((const int*)(ws + WS_TNV))[by];

    const unsigned short* xs = (const unsigned short*)(ws + WS_XS);
    unsigned short* ib = (unsigned short*)(ws + WS_INTER);

    __shared__ __align__(16) unsigned short sA[128 * 32];
    __shared__ __align__(16) unsigned short sBg[128 * 36];
    __shared__ __align__(16) unsigned short sBu[128 * 36];

    int tid = threadIdx.x, w = tid >> 6, l = tid & 63;
    int wm = w & 1, wn = w >> 1, m = l & 15, q = l >> 4;

    const unsigned short* Ab = xs + (size_t)row0 * HID;
    const float* Wg = gup + (size_t)e * HID * (2 * INTER) + (size_t)blockIdx.x * 128;
    const float* Wu = Wg + INTER;

    int c0 = tid, c1 = 256 + tid;
    int ar0 = c0 >> 2, ak0 = (c0 & 3) * 8;
    int ar1 = c1 >> 2, ak1 = (c1 & 3) * 8;
    unsigned short* aD0 = sA + (w * 64) * 8;
    unsigned short* aD1 = sA + (256 + w * 64) * 8;

    int n = tid & 127, kh = (tid >> 7) * 16;

    f32x4 accg[4][4], accu[4][4];
#pragma unroll
    for (int i = 0; i < 4; i++)
#pragma unroll
        for (int j = 0; j < 4; j++) { accg[i][j] = (f32x4)0.0f; accu[i][j] = (f32x4)0.0f; }

    for (int k0 = 0; k0 < HID; k0 += 32) {
        gld16(Ab + (size_t)ar0 * HID + k0 + ak0, aD0);
        gld16(Ab + (size_t)ar1 * HID + k0 + ak1, aD1);
#pragma unroll
        for (int g = 0; g < 4; g++) {
            int kb = kh + g * 4;
            const float* wp = Wg + (size_t)(k0 + kb) * (2 * INTER) + n;
            *(uint2*)(sBg + n * 36 + kb) =
                make_uint2(pk2(wp[0], wp[2 * INTER]), pk2(wp[4 * INTER], wp[6 * INTER]));
            const float* vp = Wu + (size_t)(k0 + kb) * (2 * INTER) + n;
            *(uint2*)(sBu + n * 36 + kb) =
                make_uint2(pk2(vp[0], vp[2 * INTER]), pk2(vp[4 * INTER], vp[6 * INTER]));
        }
        __syncthreads();

        bf16x8 af[4], bg[4], bu[4];
#pragma unroll
        for (int mi = 0; mi < 4; mi++)
            af[mi] = *(const bf16x8*)(sA + ((wm * 64 + mi * 16 + m) * 32 + q * 8));
#pragma unroll
        for (int ni = 0; ni < 4; ni++) {
            int nb = (wn * 64 + ni * 16 + m) * 36 + q * 8;
            bg[ni] = ldfrag(sBg + nb);
            bu[ni] = ldfrag(sBu + nb);
        }
#pragma unroll
        for (int mi = 0; mi < 4; mi++)
#pragma unroll
            for (int ni = 0; ni < 4; ni++) {
                accg[mi][ni] = __builtin_amdgcn_mfma_f32_16x16x32_bf16(af[mi], bg[ni], accg[mi][ni], 0, 0, 0);
                accu[mi][ni] = __builtin_amdgcn_mfma_f32_16x16x32_bf16(af[mi], bu[ni], accu[mi][ni], 0, 0, 0);
            }
        __syncthreads();
    }

#pragma unroll
    for (int mi = 0; mi < 4; mi++)
#pragma unroll
        for (int r = 0; r < 4; r++) {
            int rl = wm * 64 + mi * 16 + q * 4 + r;
            if (rl < nv) {
                size_t o = (size_t)(row0 + rl) * INTER + blockIdx.x * 128 + wn * 64 + m;
#pragma unroll
                for (int ni = 0; ni < 4; ni++) {
                    float g = accg[mi][ni][r];
                    float u = accu[mi][ni][r];
                    float s = g / (1.0f + __expf(-g));
                    ib[o + ni * 16] = f2b(s * u);
                }
            }
        }
}

__global__ __launch_bounds__(256, 2)
void gemm2_f32(char* __restrict__ ws, const float* __restrict__ dwn, float* __restrict__ out) {
    int nt = *(const int*)(ws + WS_NTILES);
    int by = blockIdx.y;
    if (by >= nt) return;
    int e    = ((const int*)(ws + WS_TEXP))[by];
    int row0 = ((const int*)(ws + WS_TROW))[by];
    int nv   = ((const int*)(ws + WS_TNV))[by];
    const int* rowtok = (const int*)(ws + WS_ROWTOK);
    const unsigned short* ib = (const unsigned short*)(ws + WS_INTER);

    __shared__ __align__(16) unsigned short sA[128 * 32];
    __shared__ __align__(16) unsigned short sB[128 * 36];

    int tid = threadIdx.x, w = tid >> 6, l = tid & 63;
    int wm = w & 1, wn = w >> 1, m = l & 15, q = l >> 4;

    const unsigned short* Ab = ib + (size_t)row0 * INTER;
    const float* W = dwn + (size_t)e * INTER * HID + (size_t)blockIdx.x * 128;

    int c0 = tid, c1 = 256 + tid;
    int ar0 = c0 >> 2, ak0 = (c0 & 3) * 8;
    int ar1 = c1 >> 2, ak1 = (c1 & 3) * 8;
    unsigned short* aD0 = sA + (w * 64) * 8;
    unsigned short* aD1 = sA + (256 + w * 64) * 8;

    int n = tid & 127, kh = (tid >> 7) * 16;

    f32x4 acc[4][4];
#pragma unroll
    for (int i = 0; i < 4; i++)
#pragma unroll
        for (int j = 0; j < 4; j++) acc[i][j] = (f32x4)0.0f;

    for (int k0 = 0; k0 < INTER; k0 += 32) {
        gld16(Ab + (size_t)ar0 * INTER + k0 + ak0, aD0);
        gld16(Ab + (size_t)ar1 * INTER + k0 + ak1, aD1);
#pragma unroll
        for (int g = 0; g < 4; g++) {
            int kb = kh + g * 4;
            const float* wp = W + (size_t)(k0 + kb) * HID + n;
            *(uint2*)(sB + n * 36 + kb) =
                make_uint2(pk2(wp[0], wp[HID]), pk2(wp[2 * HID], wp[3 * HID]));
        }
        __syncthreads();

        bf16x8 af[4], bfr[4];
#pragma unroll
        for (int mi = 0; mi < 4; mi++)
            af[mi] = *(const bf16x8*)(sA + ((wm * 64 + mi * 16 + m) * 32 + q * 8));
#pragma unroll
        for (int ni = 0; ni < 4; ni++)
            bfr[ni] = ldfrag(sB + (wn * 64 + ni * 16 + m) * 36 + q * 8);
#pragma unroll
        for (int mi = 0; mi < 4; mi++)
#pragma unroll
            for (int ni = 0; ni < 4; ni++)
                acc[mi][ni] = __builtin_amdgcn_mfma_f32_16x16x32_bf16(af[mi], bfr[ni], acc[mi][ni], 0, 0, 0);
        __syncthreads();
    }

#pragma unroll
    for (int mi = 0; mi < 4; mi++)
#pragma unroll
        for (int r = 0; r < 4; r++) {
            int rl = wm * 64 + mi * 16 + q * 4 + r;
            if (rl < nv) {
                int tok = rowtok[row0 + rl];
                size_t o = (size_t)tok * HID + blockIdx.x * 128 + wn * 64 + m;
#pragma unroll
                for (int ni = 0; ni < 4; ni++) out[o + ni * 16] = acc[mi][ni][r];
            }
        }
}

extern "C" void kernel_launch(void* const* d_in, const int* in_sizes, int n_in,
                              void* d_out, int out_size, void* d_ws, size_t ws_size,
                              hipStream_t stream) {
    const float* x   = (const float*)d_in[0];
    const int*   ids = (const int*)d_in[1];
    const float* gup = (const float*)d_in[2];
    const float* dwn = (const float*)d_in[3];
    char* ws = (char*)d_ws;

    if (ws_size >= WS_NEED_BIG) {
        // big path: pre-convert weights to bf16 transposed, pure-MFMA GEMMs.
        // down^T conversion reuses the gate_up^T region (stream-ordered after gemm1).
        hipLaunchKernelGGL(route_kernel, dim3(1), dim3(1024), 0, stream, ids, ws);
        hipLaunchKernelGGL(gather_cast, dim3(TOKENS), dim3(256), 0, stream, x, ws);
        hipLaunchKernelGGL(convT_kernel, dim3((2 * INTER) / 64, HID / 64, NEXP), dim3(256), 0, stream,
                           gup, (unsigned short*)(ws + WS_GUPT), HID, 2 * INTER);
        hipLaunchKernelGGL(gemm1_bf, dim3(16, MAXTILES), dim3(256), 0, stream, ws);
        hipLaunchKernelGGL(convT_kernel, dim3(HID / 64, INTER / 64, NEXP), dim3(256), 0, stream,
                           dwn, (unsigned short*)(ws + WS_DWNT), INTER, HID);
        hipLaunchKernelGGL(gemm2_bf, dim3(32, MAXTILES), dim3(256), 0, stream, ws, (float*)d_out);
    } else if (ws_size >= WS_NEED_SMALL) {
        // fallback: previous verified path (fp32 weights converted in-loop)
        hipLaunchKernelGGL(route_kernel, dim3(1), dim3(1024), 0, stream, ids, ws);
        hipLaunchKernelGGL(gather_cast, dim3(TOKENS), dim3(256), 0, stream, x, ws);
        hipLaunchKernelGGL(gemm1_f32, dim3(16, MAXTILES), dim3(256), 0, stream, ws, gup);
        hipLaunchKernelGGL(gemm2_f32, dim3(32, MAXTILES), dim3(256), 0, stream, ws, dwn, (float*)d_out);
    }
    // else: workspace too small — fail loudly by writing nothing
}